// Round 5
// baseline (458.853 us; speedup 1.0000x reference)
//
#include <hip/hip_runtime.h>
#include <cstdint>
#include <cstddef>

#define T_ 4
#define N_ 512
#define C_ 256
#define V_ 25
#define H_ 8

typedef _Float16 half8_t __attribute__((ext_vector_type(8)));
typedef float f32x16 __attribute__((ext_vector_type(16)));

__device__ __forceinline__ f32x16 mfma16(half8_t a, half8_t b, f32x16 c) {
  return __builtin_amdgcn_mfma_f32_32x32x16_f16(a, b, c, 0, 0, 0);
}

// ---- KW: pre-swizzled, BN-scaled, fp16-split weights ----
// Wstg: i = ((((c*4+p)*4+s)*2+m)*4+rt)*512 + lane*8 + j
//   chunks 0..5 = qkv (br=c>>1, rows (c&1)*128+..), 6..7 = proj
//   row = rt*32+(lane&31) ; k = (p*4+s)*16+(lane>>5)*8+j ; m: 0=hi,1=lo
__global__ void kw_stage(const float* __restrict__ wq, const float* __restrict__ wk,
                         const float* __restrict__ wv, const float* __restrict__ wp,
                         const float* __restrict__ qg, const float* __restrict__ qvar,
                         const float* __restrict__ kg, const float* __restrict__ kvar,
                         const float* __restrict__ vg, const float* __restrict__ vvar,
                         const float* __restrict__ pg, const float* __restrict__ pvar,
                         _Float16* __restrict__ Wstg) {
  int i = blockIdx.x * 512 + threadIdx.x;          // < 524288
  int j = i & 7, lane = (i >> 3) & 63, rt = (i >> 9) & 3, m = (i >> 11) & 1;
  int s = (i >> 12) & 3, p = (i >> 14) & 3, c = i >> 16;
  int kt = p * 4 + s;
  int row = rt * 32 + (lane & 31);
  int k = kt * 16 + (lane >> 5) * 8 + j;
  const float *w, *g, *va;
  int grow;
  if (c < 6) {
    int br = c >> 1;
    w = br == 0 ? wq : br == 1 ? wk : wv;
    g = br == 0 ? qg : br == 1 ? kg : vg;
    va = br == 0 ? qvar : br == 1 ? kvar : vvar;
    grow = (c & 1) * 128 + row;
  } else {
    w = wp; g = pg; va = pvar;
    grow = (c - 6) * 128 + row;
  }
  float sc = g[grow] / sqrtf(va[grow] + 1e-5f);
  float wv_ = w[grow * 256 + k] * sc;
  _Float16 hi = (_Float16)wv_;
  Wstg[i] = (m == 0) ? hi : (_Float16)(wv_ - (float)hi);
}

// ---- KX: fp16 hi/lo x-panels in global: X16[n][m][col=v*4+t][k], col<100 ----
__global__ void kx_stage(const float* __restrict__ x, _Float16* __restrict__ X16) {
  __shared__ float Xt[256 * 28];
  const int n = blockIdx.x, tid = threadIdx.x;
  for (int t = 0; t < 4; ++t) {
    __syncthreads();
    for (int i = tid; i < 6400; i += 256) {
      int k = i / 25, v = i - k * 25;
      Xt[k * 28 + v] = x[(size_t)(t * N_ + n) * 6400 + i];
    }
    __syncthreads();
    for (int j = tid; j < 800; j += 256) {
      int v = j >> 5, kb = j & 31, k0 = kb * 8;
      half8_t hi, lo;
#pragma unroll
      for (int e = 0; e < 8; ++e) {
        float f = Xt[(k0 + e) * 28 + v];
        _Float16 h = (_Float16)f;
        hi[e] = h;
        lo[e] = (_Float16)(f - (float)h);
      }
      size_t base = ((size_t)(2 * n) * 100 + (v * 4 + t)) * 256 + k0;
      *(half8_t*)(X16 + base) = hi;
      *(half8_t*)(X16 + base + 25600) = lo;
    }
  }
}

// Stage one 32KB phase block (4 kt) of Wstg into LDS, lane-linear.
#define STAGE_A(gidx, bufsel)                                                     \
  do {                                                                            \
    const _Float16* sp_ = Wstg + (size_t)(gidx) * 16384 + tid * 8;                \
    char* dp_ = Abuf + (bufsel) * 32768 + tid * 16;                               \
    __builtin_amdgcn_global_load_lds((const uint32_t*)(sp_),          (uint32_t*)(dp_),          16, 0, 0); \
    __builtin_amdgcn_global_load_lds((const uint32_t*)(sp_ + 4096),   (uint32_t*)(dp_ + 8192),   16, 0, 0); \
    __builtin_amdgcn_global_load_lds((const uint32_t*)(sp_ + 8192),   (uint32_t*)(dp_ + 16384),  16, 0, 0); \
    __builtin_amdgcn_global_load_lds((const uint32_t*)(sp_ + 12288),  (uint32_t*)(dp_ + 24576),  16, 0, 0); \
  } while (0)

// Ms swizzled byte offset: [col][row] f32, row-stride 256B, XOR bits 4-6
#define MS_BYTE(colx, rowx) ((colx) * 256 + (((rowx) * 4) ^ (((colx) & 7) << 4)))

// ---- K1: qkv conv (fp16-split MFMA) + BN + LIF -> spike bitmasks ----
// 8 waves = (rt = wid&3, cp = wid>>2); wave tile: 32 rows x 64 cols (2 ct)
__launch_bounds__(512, 1)
__global__ void k1_mfma(const _Float16* __restrict__ X16, const _Float16* __restrict__ Wstg,
                        const float* __restrict__ qg, const float* __restrict__ qb,
                        const float* __restrict__ qm, const float* __restrict__ qvar,
                        const float* __restrict__ kg, const float* __restrict__ kb,
                        const float* __restrict__ km, const float* __restrict__ kvar,
                        const float* __restrict__ vg, const float* __restrict__ vb,
                        const float* __restrict__ vm, const float* __restrict__ vvar,
                        uint32_t* __restrict__ masks) {
  __shared__ __align__(16) char LDSb[65536 + 32768 + 512];
  char* Abuf = LDSb;
  char* MsB = LDSb + 65536;
  float* bic = (float*)(LDSb + 65536 + 32768);

  const int n = blockIdx.x, tid = threadIdx.x;
  const int lane = tid & 63, wid = tid >> 6;
  const int rt = wid & 3, cp = wid >> 2;
  const int lr = lane & 31, lkg = lane >> 5;

  // B fragments from global panels (L3-resident), 256 VGPR
  half8_t Bh[32], Bl[32];
#pragma unroll
  for (int ct = 0; ct < 2; ++ct) {
    int col = cp * 64 + ct * 32 + lr;
    int colc = col < 100 ? col : 99;
    const _Float16* bp0 = X16 + ((size_t)(2 * n) * 100 + colc) * 256 + lkg * 8;
#pragma unroll
    for (int kt = 0; kt < 16; ++kt) {
      Bh[ct * 16 + kt] = *(const half8_t*)(bp0 + kt * 16);
      Bl[ct * 16 + kt] = *(const half8_t*)(bp0 + 25600 + kt * 16);
    }
  }
  STAGE_A(0, 0);

  for (int c = 0; c < 6; ++c) {
    const int br = c >> 1;
    f32x16 acc0 = {}, acc1 = {};
#pragma unroll
    for (int p = 0; p < 4; ++p) {
      __syncthreads();
      if (p == 0 && tid < 128) {
        int ch = (c & 1) * 128 + tid;
        const float* g  = br == 0 ? qg : br == 1 ? kg : vg;
        const float* be = br == 0 ? qb : br == 1 ? kb : vb;
        const float* mu = br == 0 ? qm : br == 1 ? km : vm;
        const float* va = br == 0 ? qvar : br == 1 ? kvar : vvar;
        float sc = g[ch] / sqrtf(va[ch] + 1e-5f);
        bic[tid] = be[ch] - mu[ch] * sc;
      }
      int gnext = c * 4 + p + 1;
      if (gnext < 24) STAGE_A(gnext, (p + 1) & 1);
#pragma unroll
      for (int s = 0; s < 4; ++s) {
        const char* kb = Abuf + (p & 1) * 32768 + s * 8192 + rt * 1024 + lane * 16;
        half8_t Ahi = *(const half8_t*)(kb);
        half8_t Alo = *(const half8_t*)(kb + 4096);
        const int kt = p * 4 + s;
        __builtin_amdgcn_s_setprio(1);
        acc0 = mfma16(Ahi, Bh[kt], acc0);
        acc1 = mfma16(Ahi, Bh[16 + kt], acc1);
        acc0 = mfma16(Ahi, Bl[kt], acc0);
        acc1 = mfma16(Ahi, Bl[16 + kt], acc1);
        acc0 = mfma16(Alo, Bh[kt], acc0);
        acc1 = mfma16(Alo, Bh[16 + kt], acc1);
        __builtin_amdgcn_s_setprio(0);
      }
    }

    // epilogue: acc -> swizzled Ms[col][row] via float4 quads
    __syncthreads();
#pragma unroll
    for (int ct = 0; ct < 2; ++ct) {
      int col = cp * 64 + ct * 32 + lr;
      if (col < 100) {
        f32x16 A = ct ? acc1 : acc0;
#pragma unroll
        for (int qq = 0; qq < 4; ++qq) {
          int rowb = rt * 32 + qq * 8 + lkg * 4;
          float4 vq = make_float4(A[qq * 4], A[qq * 4 + 1], A[qq * 4 + 2], A[qq * 4 + 3]);
          *(float4*)(MsB + MS_BYTE(col, rowb)) = vq;
        }
      }
    }
    __syncthreads();
    // LIF over t + ballot pack; tasks = (hg 0..3, v 0..24)
    const int d = lane & 31, hl = lane >> 5;
    for (int it = 0; it < 7; ++it) {
      int task = it * 16 + wid * 2 + hl;
      bool valid = task < 100;
      int hg = valid ? task / 25 : 0;
      int v = valid ? task - hg * 25 : 0;
      int row = hg * 32 + d;
      float bicv = bic[hg * 32 + d];
      float st = 0.0f;
#pragma unroll
      for (int t = 0; t < 4; ++t) {
        int colx = v * 4 + t;
        float cu = *(const float*)(MsB + MS_BYTE(colx, row)) + bicv;
        st += (cu - st) * 0.5f;
        bool sb = valid && (st >= 1.0f);
        if (st >= 1.0f) st = 0.0f;
        unsigned long long b = __ballot(sb);
        if (valid && (lane == 0 || lane == 32)) {
          uint32_t wd = (lane == 0) ? (uint32_t)b : (uint32_t)(b >> 32);
          masks[((((size_t)t * N_ + n) * 3 + br) * H_ + (c & 1) * 4 + hg) * V_ + v] = wd;
        }
      }
    }
  }
}

// ---- K2: binary attention (popcount) + attn_lif -> mask2 (exact dyadic) ----
__launch_bounds__(64)
__global__ void k2_attn(const uint32_t* __restrict__ masks, uint32_t* __restrict__ mask2) {
  __shared__ uint32_t qs[T_][V_], ks_[T_][V_], vs[T_][V_];
  const int n = blockIdx.x >> 3;
  const int h = blockIdx.x & 7;
  const int l = threadIdx.x;
  for (int i = l; i < T_ * 3 * V_; i += 64) {
    int t = i / (3 * V_);
    int r = i - t * (3 * V_);
    int br = r / V_;
    int v = r - br * V_;
    uint32_t w = masks[(((size_t)t * N_ + n) * 3 + br) * (H_ * V_) + h * V_ + v];
    if (br == 0) qs[t][v] = w;
    else if (br == 1) ks_[t][v] = w;
    else vs[t][v] = w;
  }
  __syncthreads();
  const int hi = l >> 5, d = l & 31;
  for (int vv = 0; vv < 13; ++vv) {
    int v = vv * 2 + hi;
    bool valid = (v < V_);
    int vc = valid ? v : 0;
    float st = 0.0f;
#pragma unroll
    for (int t = 0; t < 4; ++t) {
      int y = 0;
      uint32_t qmw = qs[t][vc];
#pragma unroll
      for (int w = 0; w < V_; ++w) {
        int a = __popc(qmw & ks_[t][w]);
        y += a * (int)((vs[t][w] >> d) & 1u);
      }
      float yf = 0.125f * (float)y;
      st += (yf - st) * 0.5f;
      bool s = valid && (st >= 0.5f);
      if (st >= 0.5f) st = 0.0f;
      unsigned long long b = __ballot(s);
      if (valid && (l == 0 || l == 32)) {
        uint32_t wd = (l == 0) ? (uint32_t)b : (uint32_t)(b >> 32);
        mask2[(((size_t)t * N_ + n) * V_ + v) * H_ + h] = wd;
      }
    }
  }
}

// ---- K3: proj conv (binary B, fp16-split W) + bias/BN + LIF + residual ----
__launch_bounds__(512, 1)
__global__ void k3_mfma(const float* __restrict__ x, const _Float16* __restrict__ Wstg,
                        const uint32_t* __restrict__ mask2, const float* __restrict__ bp,
                        const float* __restrict__ pg, const float* __restrict__ pb,
                        const float* __restrict__ pm, const float* __restrict__ pvar,
                        float* __restrict__ out) {
  __shared__ __align__(16) char LDSb[65536 + 32768 + 512 + 3200];
  char* Abuf = LDSb;
  char* MsB = LDSb + 65536;
  float* bic = (float*)(LDSb + 65536 + 32768);
  uint32_t* m2s = (uint32_t*)(LDSb + 65536 + 32768 + 512);

  const int n = blockIdx.x, tid = threadIdx.x;
  const int lane = tid & 63, wid = tid >> 6;
  const int rt = wid & 3, cp = wid >> 2;
  const int lr = lane & 31, lkg = lane >> 5;

  for (int i = tid; i < 800; i += 512) {
    int t = i / 200, r = i - t * 200;
    m2s[i] = mask2[(size_t)(t * N_ + n) * 200 + r];
  }
  __syncthreads();

  // binary B fragments from mask bits
  half8_t Bb[32];
#pragma unroll
  for (int ct = 0; ct < 2; ++ct) {
    int col = cp * 64 + ct * 32 + lr;
    bool valid = col < 100;
    int v = valid ? (col >> 2) : 0;
    int t = valid ? (col & 3) : 0;
#pragma unroll
    for (int kt = 0; kt < 16; ++kt) {
#pragma unroll
      for (int jj = 0; jj < 8; ++jj) {
        int k = kt * 16 + lkg * 8 + jj;
        uint32_t bit = (m2s[t * 200 + v * 8 + (k >> 5)] >> (k & 31)) & 1u;
        Bb[ct * 16 + kt][jj] = (valid && bit) ? (_Float16)1.0f : (_Float16)0.0f;
      }
    }
  }
  STAGE_A(24, 0);

  for (int c = 0; c < 2; ++c) {
    f32x16 acc0 = {}, acc1 = {};
#pragma unroll
    for (int p = 0; p < 4; ++p) {
      __syncthreads();
      if (p == 0 && tid < 128) {
        int ch = c * 128 + tid;
        float sc = pg[ch] / sqrtf(pvar[ch] + 1e-5f);
        bic[tid] = fmaf(bp[ch] - pm[ch], sc, pb[ch]);
      }
      int gnext = (6 + c) * 4 + p + 1;
      if (gnext < 32) STAGE_A(gnext, (p + 1) & 1);
#pragma unroll
      for (int s = 0; s < 4; ++s) {
        const char* kb = Abuf + (p & 1) * 32768 + s * 8192 + rt * 1024 + lane * 16;
        half8_t Ahi = *(const half8_t*)(kb);
        half8_t Alo = *(const half8_t*)(kb + 4096);
        const int kt = p * 4 + s;
        __builtin_amdgcn_s_setprio(1);
        acc0 = mfma16(Ahi, Bb[kt], acc0);
        acc1 = mfma16(Ahi, Bb[16 + kt], acc1);
        acc0 = mfma16(Alo, Bb[kt], acc0);
        acc1 = mfma16(Alo, Bb[16 + kt], acc1);
        __builtin_amdgcn_s_setprio(0);
      }
    }

    __syncthreads();
#pragma unroll
    for (int ct = 0; ct < 2; ++ct) {
      int col = cp * 64 + ct * 32 + lr;
      if (col < 100) {
        f32x16 A = ct ? acc1 : acc0;
#pragma unroll
        for (int qq = 0; qq < 4; ++qq) {
          int rowb = rt * 32 + qq * 8 + lkg * 4;
          float4 vq = make_float4(A[qq * 4], A[qq * 4 + 1], A[qq * 4 + 2], A[qq * 4 + 3]);
          *(float4*)(MsB + MS_BYTE(col, rowb)) = vq;
        }
      }
    }
    __syncthreads();
    // LIF (v_th=1.0): write spike back into Ms
    const int d = lane & 31, hl = lane >> 5;
    for (int it = 0; it < 7; ++it) {
      int task = it * 16 + wid * 2 + hl;
      bool valid = task < 100;
      int hg = valid ? task / 25 : 0;
      int v = valid ? task - hg * 25 : 0;
      int row = hg * 32 + d;
      float bicv = bic[hg * 32 + d];
      float st = 0.0f;
#pragma unroll
      for (int t = 0; t < 4; ++t) {
        int colx = v * 4 + t;
        char* mp = MsB + MS_BYTE(colx, row);
        if (valid) {
          float cu = *(const float*)(mp) + bicv;
          st += (cu - st) * 0.5f;
          float sv = (st >= 1.0f) ? 1.0f : 0.0f;
          if (st >= 1.0f) st = 0.0f;
          *(float*)(mp) = sv;
        }
      }
    }
    __syncthreads();
    // residual + store
    for (int ii = tid; ii < 12800; ii += 512) {
      int t = ii / 3200, r2 = ii - t * 3200;
      int cl = r2 / 25, v = r2 - cl * 25;
      int colx = v * 4 + t;
      float sv = *(const float*)(MsB + MS_BYTE(colx, cl));
      size_t go = (size_t)(t * N_ + n) * 6400 + (size_t)(c * 128 + cl) * 25 + v;
      out[go] = sv + x[go];
    }
  }
}

extern "C" void kernel_launch(void* const* d_in, const int* in_sizes, int n_in,
                              void* d_out, int out_size, void* d_ws, size_t ws_size,
                              hipStream_t stream) {
  const float* x    = (const float*)d_in[0];
  const float* wq   = (const float*)d_in[1];
  const float* wk   = (const float*)d_in[2];
  const float* wv   = (const float*)d_in[3];
  const float* wp   = (const float*)d_in[4];
  const float* bp   = (const float*)d_in[5];
  const float* qg   = (const float*)d_in[6];
  const float* qb   = (const float*)d_in[7];
  const float* qm   = (const float*)d_in[8];
  const float* qvar = (const float*)d_in[9];
  const float* kg   = (const float*)d_in[10];
  const float* kb   = (const float*)d_in[11];
  const float* km   = (const float*)d_in[12];
  const float* kvar = (const float*)d_in[13];
  const float* vg   = (const float*)d_in[14];
  const float* vb   = (const float*)d_in[15];
  const float* vm   = (const float*)d_in[16];
  const float* vvar = (const float*)d_in[17];
  const float* pg   = (const float*)d_in[18];
  const float* pb   = (const float*)d_in[19];
  const float* pm   = (const float*)d_in[20];
  const float* pvar = (const float*)d_in[21];

  _Float16* Wstg = (_Float16*)d_ws;                      // 1 MB
  _Float16* X16  = (_Float16*)d_ws + 524288;             // 52.4 MB panels
  uint32_t* masks = (uint32_t*)((char*)d_ws + 1048576 + 52428800);
  uint32_t* mask2 = masks + 1228800;

  kw_stage<<<1024, 512, 0, stream>>>(wq, wk, wv, wp, qg, qvar, kg, kvar,
                                     vg, vvar, pg, pvar, Wstg);
  kx_stage<<<512, 256, 0, stream>>>(x, X16);
  k1_mfma<<<512, 512, 0, stream>>>(X16, Wstg, qg, qb, qm, qvar, kg, kb, km, kvar,
                                   vg, vb, vm, vvar, masks);
  k2_attn<<<4096, 64, 0, stream>>>(masks, mask2);
  k3_mfma<<<512, 512, 0, stream>>>(x, Wstg, mask2, bp, pg, pb, pm, pvar, (float*)d_out);
}

// Round 6
// 294.292 us; speedup vs baseline: 1.5592x; 1.5592x over previous
//
#include <hip/hip_runtime.h>
#include <cstdint>
#include <cstddef>

#define T_ 4
#define N_ 512
#define C_ 256
#define V_ 25
#define H_ 8

typedef _Float16 half8_t __attribute__((ext_vector_type(8)));
typedef float f32x16 __attribute__((ext_vector_type(16)));

__device__ __forceinline__ f32x16 mfma16(half8_t a, half8_t b, f32x16 c) {
  return __builtin_amdgcn_mfma_f32_32x32x16_f16(a, b, c, 0, 0, 0);
}

// ---- KW: pre-swizzled, BN-scaled, fp16-split weights ----
// Wstg: i = ((((c*4+p)*4+s)*2+m)*4+rt)*512 + lane*8 + j
//   chunks 0..5 = qkv (br=c>>1, rows (c&1)*128+..), 6..7 = proj
//   row = rt*32+(lane&31) ; k = (p*4+s)*16+(lane>>5)*8+j ; m: 0=hi,1=lo
__global__ void kw_stage(const float* __restrict__ wq, const float* __restrict__ wk,
                         const float* __restrict__ wv, const float* __restrict__ wp,
                         const float* __restrict__ qg, const float* __restrict__ qvar,
                         const float* __restrict__ kg, const float* __restrict__ kvar,
                         const float* __restrict__ vg, const float* __restrict__ vvar,
                         const float* __restrict__ pg, const float* __restrict__ pvar,
                         _Float16* __restrict__ Wstg) {
  int i = blockIdx.x * 512 + threadIdx.x;          // < 524288
  int j = i & 7, lane = (i >> 3) & 63, rt = (i >> 9) & 3, m = (i >> 11) & 1;
  int s = (i >> 12) & 3, p = (i >> 14) & 3, c = i >> 16;
  int kt = p * 4 + s;
  int row = rt * 32 + (lane & 31);
  int k = kt * 16 + (lane >> 5) * 8 + j;
  const float *w, *g, *va;
  int grow;
  if (c < 6) {
    int br = c >> 1;
    w = br == 0 ? wq : br == 1 ? wk : wv;
    g = br == 0 ? qg : br == 1 ? kg : vg;
    va = br == 0 ? qvar : br == 1 ? kvar : vvar;
    grow = (c & 1) * 128 + row;
  } else {
    w = wp; g = pg; va = pvar;
    grow = (c - 6) * 128 + row;
  }
  float sc = g[grow] / sqrtf(va[grow] + 1e-5f);
  float wv_ = w[grow * 256 + k] * sc;
  _Float16 hi = (_Float16)wv_;
  Wstg[i] = (m == 0) ? hi : (_Float16)(wv_ - (float)hi);
}

// ---- KX: fp16 hi/lo x-panels, kt-major coalesced ----
// X16 idx(n,m,kt,col,e) = (((n*2+m)*16 + kt)*100 + col)*16 + e ;  col = t*25+v ; k = kt*16+e
__global__ void kx_stage(const float* __restrict__ x, _Float16* __restrict__ X16) {
  __shared__ float Xt[256 * 28];
  const int n = blockIdx.x, tid = threadIdx.x;   // 256 threads
  for (int t = 0; t < 4; ++t) {
    __syncthreads();
    for (int i = tid; i < 6400; i += 256) {
      int k = i / 25, v = i - k * 25;
      Xt[k * 28 + v] = x[(size_t)(t * N_ + n) * 6400 + i];
    }
    __syncthreads();
    // 800 tasks: (kt 16) x (v 25) x (lkg 2), contiguous writes per kt
    for (int jj = tid; jj < 800; jj += 256) {
      int kt = jj / 50, r = jj - kt * 50;
      int v = r >> 1, lkg = r & 1;
      int k0 = kt * 16 + lkg * 8;
      half8_t hi, lo;
#pragma unroll
      for (int e = 0; e < 8; ++e) {
        float f = Xt[(k0 + e) * 28 + v];
        _Float16 h = (_Float16)f;
        hi[e] = h;
        lo[e] = (_Float16)(f - (float)h);
      }
      int col = t * 25 + v;
      size_t bhi = ((((size_t)n * 2 + 0) * 16 + kt) * 100 + col) * 16 + lkg * 8;
      size_t blo = ((((size_t)n * 2 + 1) * 16 + kt) * 100 + col) * 16 + lkg * 8;
      *(half8_t*)(X16 + bhi) = hi;
      *(half8_t*)(X16 + blo) = lo;
    }
  }
}

// Stage one 32KB phase block (4 kt) of Wstg into LDS, lane-linear.
#define STAGE_A(gidx, bufsel)                                                     \
  do {                                                                            \
    const _Float16* sp_ = Wstg + (size_t)(gidx) * 16384 + tid * 8;                \
    char* dp_ = Abuf + (bufsel) * 32768 + tid * 16;                               \
    __builtin_amdgcn_global_load_lds((const uint32_t*)(sp_),          (uint32_t*)(dp_),          16, 0, 0); \
    __builtin_amdgcn_global_load_lds((const uint32_t*)(sp_ + 4096),   (uint32_t*)(dp_ + 8192),   16, 0, 0); \
    __builtin_amdgcn_global_load_lds((const uint32_t*)(sp_ + 8192),   (uint32_t*)(dp_ + 16384),  16, 0, 0); \
    __builtin_amdgcn_global_load_lds((const uint32_t*)(sp_ + 12288),  (uint32_t*)(dp_ + 24576),  16, 0, 0); \
  } while (0)

// Ms swizzled byte offset: [col][row] f32, col-stride 256B, XOR bits 4-6
#define MS_BYTE(colx, rowx) ((colx) * 256 + (((rowx) * 4) ^ (((colx) & 7) << 4)))

// ---- K1: qkv conv (fp16-split MFMA, even/odd K-split waves) + BN + LIF -> masks ----
// 8 waves: ks = wid&1 (K parity), cp = (wid>>1)&1 (col 64-group), rt2 = wid>>2 (row 64-group)
__launch_bounds__(512, 2)
__global__ void k1_mfma(const _Float16* __restrict__ X16, const _Float16* __restrict__ Wstg,
                        const float* __restrict__ qg, const float* __restrict__ qb,
                        const float* __restrict__ qm, const float* __restrict__ qvar,
                        const float* __restrict__ kg, const float* __restrict__ kb,
                        const float* __restrict__ km, const float* __restrict__ kvar,
                        const float* __restrict__ vg, const float* __restrict__ vb,
                        const float* __restrict__ vm, const float* __restrict__ vvar,
                        uint32_t* __restrict__ masks) {
  __shared__ __align__(16) char LDSb[65536 + 32768 + 512];
  char* Abuf = LDSb;
  char* MsB = LDSb + 65536;
  float* bic = (float*)(LDSb + 65536 + 32768);

  const int n = blockIdx.x, tid = threadIdx.x;
  const int lane = tid & 63, wid = tid >> 6;
  const int ks = wid & 1, cp = (wid >> 1) & 1, rt2 = wid >> 2;
  const int lr = lane & 31, lkg = lane >> 5;

  // B-bank: this wave's K-parity half, 2 col-tiles. 32 half8 = 128 VGPR.
  half8_t Bh[16], Bl[16];
#pragma unroll
  for (int ct = 0; ct < 2; ++ct) {
    int col = cp * 64 + ct * 32 + lr;
    if (col > 99) col = 99;
#pragma unroll
    for (int ktl = 0; ktl < 8; ++ktl) {
      int kt = ktl * 2 + ks;
      Bh[ct * 8 + ktl] = *(const half8_t*)(X16 + ((((size_t)n * 2 + 0) * 16 + kt) * 100 + col) * 16 + lkg * 8);
      Bl[ct * 8 + ktl] = *(const half8_t*)(X16 + ((((size_t)n * 2 + 1) * 16 + kt) * 100 + col) * 16 + lkg * 8);
    }
  }
  STAGE_A(0, 0);

  for (int c = 0; c < 6; ++c) {
    const int br = c >> 1;
    f32x16 acc00 = {}, acc01 = {}, acc10 = {}, acc11 = {};
#pragma unroll
    for (int p = 0; p < 4; ++p) {
      __syncthreads();          // phase-p A-tile resident
      if (p == 0 && tid < 128) {
        int ch = (c & 1) * 128 + tid;
        const float* g  = br == 0 ? qg : br == 1 ? kg : vg;
        const float* be = br == 0 ? qb : br == 1 ? kb : vb;
        const float* mu = br == 0 ? qm : br == 1 ? km : vm;
        const float* va = br == 0 ? qvar : br == 1 ? kvar : vvar;
        float sc = g[ch] / sqrtf(va[ch] + 1e-5f);
        bic[tid] = be[ch] - mu[ch] * sc;
      }
      int gnext = c * 4 + p + 1;
      if (gnext < 24) STAGE_A(gnext, (p + 1) & 1);
#pragma unroll
      for (int s2 = 0; s2 < 2; ++s2) {
        const int s = s2 * 2 + ks;            // this wave's kt slots in the phase
        const int bi = p * 2 + s2;            // B-bank index (ktl)
        const char* kb = Abuf + (p & 1) * 32768 + s * 8192 + (rt2 * 2) * 1024 + lane * 16;
        half8_t Ah0 = *(const half8_t*)(kb);
        half8_t Ah1 = *(const half8_t*)(kb + 1024);
        half8_t Al0 = *(const half8_t*)(kb + 4096);
        half8_t Al1 = *(const half8_t*)(kb + 4096 + 1024);
        __builtin_amdgcn_s_setprio(1);
        acc00 = mfma16(Ah0, Bh[bi], acc00);
        acc01 = mfma16(Ah0, Bh[8 + bi], acc01);
        acc10 = mfma16(Ah1, Bh[bi], acc10);
        acc11 = mfma16(Ah1, Bh[8 + bi], acc11);
        acc00 = mfma16(Ah0, Bl[bi], acc00);
        acc01 = mfma16(Ah0, Bl[8 + bi], acc01);
        acc10 = mfma16(Ah1, Bl[bi], acc10);
        acc11 = mfma16(Ah1, Bl[8 + bi], acc11);
        acc00 = mfma16(Al0, Bh[bi], acc00);
        acc01 = mfma16(Al0, Bh[8 + bi], acc01);
        acc10 = mfma16(Al1, Bh[bi], acc10);
        acc11 = mfma16(Al1, Bh[8 + bi], acc11);
        __builtin_amdgcn_s_setprio(0);
      }
    }

    // epilogue: ks0 writes partials, ks1 adds its partials, then LIF+pack
    __syncthreads();
    if (ks == 0) {
#pragma unroll
      for (int rsub = 0; rsub < 2; ++rsub) {
#pragma unroll
        for (int ct = 0; ct < 2; ++ct) {
          int col = cp * 64 + ct * 32 + lr;
          if (col < 100) {
            f32x16 A = rsub ? (ct ? acc11 : acc10) : (ct ? acc01 : acc00);
#pragma unroll
            for (int qq = 0; qq < 4; ++qq) {
              int rowb = (rt2 * 2 + rsub) * 32 + qq * 8 + lkg * 4;
              *(float4*)(MsB + MS_BYTE(col, rowb)) =
                  make_float4(A[qq * 4], A[qq * 4 + 1], A[qq * 4 + 2], A[qq * 4 + 3]);
            }
          }
        }
      }
    }
    __syncthreads();
    if (ks == 1) {
#pragma unroll
      for (int rsub = 0; rsub < 2; ++rsub) {
#pragma unroll
        for (int ct = 0; ct < 2; ++ct) {
          int col = cp * 64 + ct * 32 + lr;
          if (col < 100) {
            f32x16 A = rsub ? (ct ? acc11 : acc10) : (ct ? acc01 : acc00);
#pragma unroll
            for (int qq = 0; qq < 4; ++qq) {
              int rowb = (rt2 * 2 + rsub) * 32 + qq * 8 + lkg * 4;
              float4* mp = (float4*)(MsB + MS_BYTE(col, rowb));
              float4 old = *mp;
              *mp = make_float4(old.x + A[qq * 4], old.y + A[qq * 4 + 1],
                                old.z + A[qq * 4 + 2], old.w + A[qq * 4 + 3]);
            }
          }
        }
      }
    }
    __syncthreads();
    // LIF over t + ballot pack; tasks = (hg 0..3, v 0..24); col = t*25+v
    const int d = lane & 31, hl = lane >> 5;
    for (int it = 0; it < 7; ++it) {
      int task = it * 16 + wid * 2 + hl;
      bool valid = task < 100;
      int hg = valid ? task / 25 : 0;
      int v = valid ? task - hg * 25 : 0;
      int row = hg * 32 + d;
      float bicv = bic[row];
      float st = 0.0f;
#pragma unroll
      for (int t = 0; t < 4; ++t) {
        int colx = t * 25 + v;
        float cu = *(const float*)(MsB + MS_BYTE(colx, row)) + bicv;
        st += (cu - st) * 0.5f;
        bool sb = valid && (st >= 1.0f);
        if (st >= 1.0f) st = 0.0f;
        unsigned long long b = __ballot(sb);
        if (valid && (lane == 0 || lane == 32)) {
          uint32_t wd = (lane == 0) ? (uint32_t)b : (uint32_t)(b >> 32);
          masks[((((size_t)t * N_ + n) * 3 + br) * H_ + (c & 1) * 4 + hg) * V_ + v] = wd;
        }
      }
    }
  }
}

// ---- K2: binary attention (popcount) + attn_lif -> mask2 (exact dyadic) ----
__launch_bounds__(64)
__global__ void k2_attn(const uint32_t* __restrict__ masks, uint32_t* __restrict__ mask2) {
  __shared__ uint32_t qs[T_][V_], ks_[T_][V_], vs[T_][V_];
  const int n = blockIdx.x >> 3;
  const int h = blockIdx.x & 7;
  const int l = threadIdx.x;
  for (int i = l; i < T_ * 3 * V_; i += 64) {
    int t = i / (3 * V_);
    int r = i - t * (3 * V_);
    int br = r / V_;
    int v = r - br * V_;
    uint32_t w = masks[(((size_t)t * N_ + n) * 3 + br) * (H_ * V_) + h * V_ + v];
    if (br == 0) qs[t][v] = w;
    else if (br == 1) ks_[t][v] = w;
    else vs[t][v] = w;
  }
  __syncthreads();
  const int hi = l >> 5, d = l & 31;
  for (int vv = 0; vv < 13; ++vv) {
    int v = vv * 2 + hi;
    bool valid = (v < V_);
    int vc = valid ? v : 0;
    float st = 0.0f;
#pragma unroll
    for (int t = 0; t < 4; ++t) {
      int y = 0;
      uint32_t qmw = qs[t][vc];
#pragma unroll
      for (int w = 0; w < V_; ++w) {
        int a = __popc(qmw & ks_[t][w]);
        y += a * (int)((vs[t][w] >> d) & 1u);
      }
      float yf = 0.125f * (float)y;
      st += (yf - st) * 0.5f;
      bool s = valid && (st >= 0.5f);
      if (st >= 0.5f) st = 0.0f;
      unsigned long long b = __ballot(s);
      if (valid && (l == 0 || l == 32)) {
        uint32_t wd = (l == 0) ? (uint32_t)b : (uint32_t)(b >> 32);
        mask2[(((size_t)t * N_ + n) * V_ + v) * H_ + h] = wd;
      }
    }
  }
}

// ---- K3: proj conv (binary B, fp16-split W) + bias/BN + LIF + residual ----
// 8 waves = rt (wid&3, row 32-tile) x cp (wid>>2, col 64-group); B full-K (128 VGPR)
__launch_bounds__(512, 2)
__global__ void k3_mfma(const float* __restrict__ x, const _Float16* __restrict__ Wstg,
                        const uint32_t* __restrict__ mask2, const float* __restrict__ bp,
                        const float* __restrict__ pg, const float* __restrict__ pb,
                        const float* __restrict__ pm, const float* __restrict__ pvar,
                        float* __restrict__ out) {
  __shared__ __align__(16) char LDSb[65536 + 32768 + 512 + 3200];
  char* Abuf = LDSb;
  char* MsB = LDSb + 65536;
  float* bic = (float*)(LDSb + 65536 + 32768);
  uint32_t* m2s = (uint32_t*)(LDSb + 65536 + 32768 + 512);

  const int n = blockIdx.x, tid = threadIdx.x;
  const int lane = tid & 63, wid = tid >> 6;
  const int rt = wid & 3, cp = wid >> 2;
  const int lr = lane & 31, lkg = lane >> 5;

  for (int i = tid; i < 800; i += 512) {
    int t = i / 200, r = i - t * 200;
    m2s[i] = mask2[(size_t)(t * N_ + n) * 200 + r];
  }
  __syncthreads();

  // binary B fragments from mask bits; col = t*25+v
  half8_t Bb[32];
#pragma unroll
  for (int ct = 0; ct < 2; ++ct) {
    int col = cp * 64 + ct * 32 + lr;
    bool valid = col < 100;
    int cc = valid ? col : 0;
    int t = cc / 25, v = cc - t * 25;
#pragma unroll
    for (int kt = 0; kt < 16; ++kt) {
#pragma unroll
      for (int jj = 0; jj < 8; ++jj) {
        int k = kt * 16 + lkg * 8 + jj;
        uint32_t bit = (m2s[t * 200 + v * 8 + (k >> 5)] >> (k & 31)) & 1u;
        Bb[ct * 16 + kt][jj] = (valid && bit) ? (_Float16)1.0f : (_Float16)0.0f;
      }
    }
  }
  STAGE_A(24, 0);

  for (int c = 0; c < 2; ++c) {
    f32x16 acc0 = {}, acc1 = {};
#pragma unroll
    for (int p = 0; p < 4; ++p) {
      __syncthreads();
      if (p == 0 && tid < 128) {
        int ch = c * 128 + tid;
        float sc = pg[ch] / sqrtf(pvar[ch] + 1e-5f);
        bic[tid] = fmaf(bp[ch] - pm[ch], sc, pb[ch]);
      }
      int gnext = (6 + c) * 4 + p + 1;
      if (gnext < 32) STAGE_A(gnext, (p + 1) & 1);
#pragma unroll
      for (int s = 0; s < 4; ++s) {
        const char* kb = Abuf + (p & 1) * 32768 + s * 8192 + rt * 1024 + lane * 16;
        half8_t Ahi = *(const half8_t*)(kb);
        half8_t Alo = *(const half8_t*)(kb + 4096);
        const int kt = p * 4 + s;
        __builtin_amdgcn_s_setprio(1);
        acc0 = mfma16(Ahi, Bb[kt], acc0);
        acc1 = mfma16(Ahi, Bb[16 + kt], acc1);
        acc0 = mfma16(Alo, Bb[kt], acc0);
        acc1 = mfma16(Alo, Bb[16 + kt], acc1);
        __builtin_amdgcn_s_setprio(0);
      }
    }

    __syncthreads();
#pragma unroll
    for (int ct = 0; ct < 2; ++ct) {
      int col = cp * 64 + ct * 32 + lr;
      if (col < 100) {
        f32x16 A = ct ? acc1 : acc0;
#pragma unroll
        for (int qq = 0; qq < 4; ++qq) {
          int rowb = rt * 32 + qq * 8 + lkg * 4;
          *(float4*)(MsB + MS_BYTE(col, rowb)) =
              make_float4(A[qq * 4], A[qq * 4 + 1], A[qq * 4 + 2], A[qq * 4 + 3]);
        }
      }
    }
    __syncthreads();
    // LIF (v_th=1.0): write spike back into Ms; col = t*25+v
    const int d = lane & 31, hl = lane >> 5;
    for (int it = 0; it < 7; ++it) {
      int task = it * 16 + wid * 2 + hl;
      bool valid = task < 100;
      int hg = valid ? task / 25 : 0;
      int v = valid ? task - hg * 25 : 0;
      int row = hg * 32 + d;
      float bicv = bic[row];
      float st = 0.0f;
#pragma unroll
      for (int t = 0; t < 4; ++t) {
        int colx = t * 25 + v;
        char* mp = MsB + MS_BYTE(colx, row);
        if (valid) {
          float cu = *(const float*)(mp) + bicv;
          st += (cu - st) * 0.5f;
          float sv = (st >= 1.0f) ? 1.0f : 0.0f;
          if (st >= 1.0f) st = 0.0f;
          *(float*)(mp) = sv;
        }
      }
    }
    __syncthreads();
    // residual + store (coalesced)
    for (int ii = tid; ii < 12800; ii += 512) {
      int t = ii / 3200, r2 = ii - t * 3200;
      int cl = r2 / 25, v = r2 - cl * 25;
      int colx = t * 25 + v;
      float sv = *(const float*)(MsB + MS_BYTE(colx, cl));
      size_t go = (size_t)(t * N_ + n) * 6400 + (size_t)(c * 128 + cl) * 25 + v;
      out[go] = sv + x[go];
    }
  }
}

extern "C" void kernel_launch(void* const* d_in, const int* in_sizes, int n_in,
                              void* d_out, int out_size, void* d_ws, size_t ws_size,
                              hipStream_t stream) {
  const float* x    = (const float*)d_in[0];
  const float* wq   = (const float*)d_in[1];
  const float* wk   = (const float*)d_in[2];
  const float* wv   = (const float*)d_in[3];
  const float* wp   = (const float*)d_in[4];
  const float* bp   = (const float*)d_in[5];
  const float* qg   = (const float*)d_in[6];
  const float* qb   = (const float*)d_in[7];
  const float* qm   = (const float*)d_in[8];
  const float* qvar = (const float*)d_in[9];
  const float* kg   = (const float*)d_in[10];
  const float* kb   = (const float*)d_in[11];
  const float* km   = (const float*)d_in[12];
  const float* kvar = (const float*)d_in[13];
  const float* vg   = (const float*)d_in[14];
  const float* vb   = (const float*)d_in[15];
  const float* vm   = (const float*)d_in[16];
  const float* vvar = (const float*)d_in[17];
  const float* pg   = (const float*)d_in[18];
  const float* pb   = (const float*)d_in[19];
  const float* pm   = (const float*)d_in[20];
  const float* pvar = (const float*)d_in[21];

  _Float16* Wstg = (_Float16*)d_ws;                      // 1 MB
  _Float16* X16  = (_Float16*)d_ws + 524288;             // 52.4 MB panels
  uint32_t* masks = (uint32_t*)((char*)d_ws + 1048576 + 52428800);
  uint32_t* mask2 = masks + 1228800;

  kw_stage<<<1024, 512, 0, stream>>>(wq, wk, wv, wp, qg, qvar, kg, kvar,
                                     vg, vvar, pg, pvar, Wstg);
  kx_stage<<<512, 256, 0, stream>>>(x, X16);
  k1_mfma<<<512, 512, 0, stream>>>(X16, Wstg, qg, qb, qm, qvar, kg, kb, km, kvar,
                                   vg, vb, vm, vvar, masks);
  k2_attn<<<4096, 64, 0, stream>>>(masks, mask2);
  k3_mfma<<<512, 512, 0, stream>>>(x, Wstg, mask2, bp, pg, pb, pm, pvar, (float*)d_out);
}

// Round 7
// 289.934 us; speedup vs baseline: 1.5826x; 1.0150x over previous
//
#include <hip/hip_runtime.h>
#include <cstdint>
#include <cstddef>

#define T_ 4
#define N_ 512
#define C_ 256
#define V_ 25
#define H_ 8

typedef _Float16 half8_t __attribute__((ext_vector_type(8)));
typedef float f32x16 __attribute__((ext_vector_type(16)));

__device__ __forceinline__ f32x16 mfma16(half8_t a, half8_t b, f32x16 c) {
  return __builtin_amdgcn_mfma_f32_32x32x16_f16(a, b, c, 0, 0, 0);
}

#define WAITV(n) asm volatile("s_waitcnt vmcnt(" #n ")" ::: "memory")
#define BAR_A()  do { __builtin_amdgcn_s_barrier(); __builtin_amdgcn_sched_barrier(0); } while (0)
#define BAR_B()  do { asm volatile("" ::: "memory"); __builtin_amdgcn_s_barrier(); \
                      __builtin_amdgcn_sched_barrier(0); } while (0)
#define EPI_BAR() do { asm volatile("s_waitcnt lgkmcnt(0)" ::: "memory"); \
                       __builtin_amdgcn_s_barrier(); __builtin_amdgcn_sched_barrier(0); } while (0)

// ---- KW: pre-swizzled, BN-scaled, fp16-split weights ----
__global__ void kw_stage(const float* __restrict__ wq, const float* __restrict__ wk,
                         const float* __restrict__ wv, const float* __restrict__ wp,
                         const float* __restrict__ qg, const float* __restrict__ qvar,
                         const float* __restrict__ kg, const float* __restrict__ kvar,
                         const float* __restrict__ vg, const float* __restrict__ vvar,
                         const float* __restrict__ pg, const float* __restrict__ pvar,
                         _Float16* __restrict__ Wstg) {
  int i = blockIdx.x * 512 + threadIdx.x;          // < 524288
  int j = i & 7, lane = (i >> 3) & 63, rt = (i >> 9) & 3, m = (i >> 11) & 1;
  int s = (i >> 12) & 3, p = (i >> 14) & 3, c = i >> 16;
  int kt = p * 4 + s;
  int row = rt * 32 + (lane & 31);
  int k = kt * 16 + (lane >> 5) * 8 + j;
  const float *w, *g, *va;
  int grow;
  if (c < 6) {
    int br = c >> 1;
    w = br == 0 ? wq : br == 1 ? wk : wv;
    g = br == 0 ? qg : br == 1 ? kg : vg;
    va = br == 0 ? qvar : br == 1 ? kvar : vvar;
    grow = (c & 1) * 128 + row;
  } else {
    w = wp; g = pg; va = pvar;
    grow = (c - 6) * 128 + row;
  }
  float sc = g[grow] / sqrtf(va[grow] + 1e-5f);
  float wv_ = w[grow * 256 + k] * sc;
  _Float16 hi = (_Float16)wv_;
  Wstg[i] = (m == 0) ? hi : (_Float16)(wv_ - (float)hi);
}

// ---- KX: fp16 hi/lo x-panels, kt-major coalesced ----
__global__ void kx_stage(const float* __restrict__ x, _Float16* __restrict__ X16) {
  __shared__ float Xt[256 * 28];
  const int n = blockIdx.x, tid = threadIdx.x;   // 256 threads
  for (int t = 0; t < 4; ++t) {
    __syncthreads();
    for (int i = tid; i < 6400; i += 256) {
      int k = i / 25, v = i - k * 25;
      Xt[k * 28 + v] = x[(size_t)(t * N_ + n) * 6400 + i];
    }
    __syncthreads();
    for (int jj = tid; jj < 800; jj += 256) {
      int kt = jj / 50, r = jj - kt * 50;
      int v = r >> 1, lkg = r & 1;
      int k0 = kt * 16 + lkg * 8;
      half8_t hi, lo;
#pragma unroll
      for (int e = 0; e < 8; ++e) {
        float f = Xt[(k0 + e) * 28 + v];
        _Float16 h = (_Float16)f;
        hi[e] = h;
        lo[e] = (_Float16)(f - (float)h);
      }
      int col = t * 25 + v;
      size_t bhi = ((((size_t)n * 2 + 0) * 16 + kt) * 100 + col) * 16 + lkg * 8;
      size_t blo = ((((size_t)n * 2 + 1) * 16 + kt) * 100 + col) * 16 + lkg * 8;
      *(half8_t*)(X16 + bhi) = hi;
      *(half8_t*)(X16 + blo) = lo;
    }
  }
}

// Stage one 32KB phase block (4 kt) of Wstg into LDS, lane-linear.
#define STAGE_A(gidx, bufsel)                                                     \
  do {                                                                            \
    const _Float16* sp_ = Wstg + (size_t)(gidx) * 16384 + tid * 8;                \
    char* dp_ = Abuf + (bufsel) * 32768 + tid * 16;                               \
    __builtin_amdgcn_global_load_lds((const uint32_t*)(sp_),          (uint32_t*)(dp_),          16, 0, 0); \
    __builtin_amdgcn_global_load_lds((const uint32_t*)(sp_ + 4096),   (uint32_t*)(dp_ + 8192),   16, 0, 0); \
    __builtin_amdgcn_global_load_lds((const uint32_t*)(sp_ + 8192),   (uint32_t*)(dp_ + 16384),  16, 0, 0); \
    __builtin_amdgcn_global_load_lds((const uint32_t*)(sp_ + 12288),  (uint32_t*)(dp_ + 24576),  16, 0, 0); \
  } while (0)

// Ms swizzled byte offset (UNCHANGED — bit-exact verified r4-r6)
#define MS_BYTE(colx, rowx) ((colx) * 256 + (((rowx) * 4) ^ (((colx) & 7) << 4)))

// ---- K1: qkv conv (fp16-split MFMA, even/odd K-split waves) + BN + LIF -> masks ----
// depth-2 counted-vmcnt pipeline, 3 rotating A-buffers
__launch_bounds__(512, 2)
__global__ void k1_mfma(const _Float16* __restrict__ X16, const _Float16* __restrict__ Wstg,
                        const float* __restrict__ qg, const float* __restrict__ qb,
                        const float* __restrict__ qm, const float* __restrict__ qvar,
                        const float* __restrict__ kg, const float* __restrict__ kb,
                        const float* __restrict__ km, const float* __restrict__ kvar,
                        const float* __restrict__ vg, const float* __restrict__ vb,
                        const float* __restrict__ vm, const float* __restrict__ vvar,
                        uint32_t* __restrict__ masks) {
  __shared__ __align__(16) char LDSb[143744];
  char* Abuf = LDSb;                          // 3 x 32768
  char* MsB  = LDSb + 98304;                  // 32768
  float* bicL = (float*)(LDSb + 131072);      // 768 f32
  uint32_t* mkL = (uint32_t*)(LDSb + 134144); // 2400 u32

  const int n = blockIdx.x, tid = threadIdx.x;
  const int lane = tid & 63, wid = tid >> 6;
  const int ks = wid & 1, cp = (wid >> 1) & 1, rt2 = wid >> 2;
  const int lr = lane & 31, lkg = lane >> 5;

  // hoisted BN-bias table for all 6 chunks
  for (int i = tid; i < 768; i += 512) {
    int cc = i >> 7, row = i & 127;
    int br = cc >> 1, ch = (cc & 1) * 128 + row;
    const float* g  = br == 0 ? qg : br == 1 ? kg : vg;
    const float* be = br == 0 ? qb : br == 1 ? kb : vb;
    const float* mu = br == 0 ? qm : br == 1 ? km : vm;
    const float* va = br == 0 ? qvar : br == 1 ? kvar : vvar;
    float sc = g[ch] / sqrtf(va[ch] + 1e-5f);
    bicL[i] = be[ch] - mu[ch] * sc;
  }

  // B-bank: this wave's K-parity half, 2 col-tiles (128 VGPR)
  half8_t Bh[16], Bl[16];
#pragma unroll
  for (int ct = 0; ct < 2; ++ct) {
    int col = cp * 64 + ct * 32 + lr;
    if (col > 99) col = 99;
#pragma unroll
    for (int ktl = 0; ktl < 8; ++ktl) {
      int kt = ktl * 2 + ks;
      Bh[ct * 8 + ktl] = *(const half8_t*)(X16 + ((((size_t)n * 2 + 0) * 16 + kt) * 100 + col) * 16 + lkg * 8);
      Bl[ct * 8 + ktl] = *(const half8_t*)(X16 + ((((size_t)n * 2 + 1) * 16 + kt) * 100 + col) * 16 + lkg * 8);
    }
  }
  __builtin_amdgcn_sched_barrier(0);
  WAITV(0);                      // B-bank + bic global reads fully drained
  STAGE_A(0, 0);
  STAGE_A(1, 1);
  STAGE_A(2, 2);

  for (int c = 0; c < 6; ++c) {
    const int br = c >> 1;
    f32x16 acc00 = {}, acc01 = {}, acc10 = {}, acc11 = {};
#pragma unroll
    for (int p = 0; p < 4; ++p) {
      // barrier A: phase-p tile resident (counted wait, keeps 2 STAGEs in flight)
      if (c < 5) { WAITV(8); }
      else {
        if (p < 2) { WAITV(8); } else if (p == 2) { WAITV(4); } else { WAITV(0); }
      }
      BAR_A();
      const int bsel = (c + p) % 3;          // (c*4+p) % 3
      const char* bufb = Abuf + bsel * 32768;
#pragma unroll
      for (int s2 = 0; s2 < 2; ++s2) {
        const int s = s2 * 2 + ks;
        const int bi = p * 2 + s2;
        const char* kb = bufb + s * 8192 + (rt2 * 2) * 1024 + lane * 16;
        half8_t Ah0 = *(const half8_t*)(kb);
        half8_t Ah1 = *(const half8_t*)(kb + 1024);
        half8_t Al0 = *(const half8_t*)(kb + 4096);
        half8_t Al1 = *(const half8_t*)(kb + 4096 + 1024);
        __builtin_amdgcn_s_setprio(1);
        acc00 = mfma16(Ah0, Bh[bi], acc00);
        acc01 = mfma16(Ah0, Bh[8 + bi], acc01);
        acc10 = mfma16(Ah1, Bh[bi], acc10);
        acc11 = mfma16(Ah1, Bh[8 + bi], acc11);
        acc00 = mfma16(Ah0, Bl[bi], acc00);
        acc01 = mfma16(Ah0, Bl[8 + bi], acc01);
        acc10 = mfma16(Ah1, Bl[bi], acc10);
        acc11 = mfma16(Ah1, Bl[8 + bi], acc11);
        acc00 = mfma16(Al0, Bh[bi], acc00);
        acc01 = mfma16(Al0, Bh[8 + bi], acc01);
        acc10 = mfma16(Al1, Bh[bi], acc10);
        acc11 = mfma16(Al1, Bh[8 + bi], acc11);
        __builtin_amdgcn_s_setprio(0);
      }
      // barrier B: all waves done reading buf -> safe to overwrite with STAGE(p+3)
      BAR_B();
      int gn = c * 4 + p + 3;
      if (gn < 24) STAGE_A(gn, bsel);
    }

    // epilogue: ks0 writes partials, ks1 adds, then LIF+pack (raw barriers only)
    if (ks == 0) {
#pragma unroll
      for (int rsub = 0; rsub < 2; ++rsub) {
#pragma unroll
        for (int ct = 0; ct < 2; ++ct) {
          int col = cp * 64 + ct * 32 + lr;
          if (col < 100) {
            f32x16 A = rsub ? (ct ? acc11 : acc10) : (ct ? acc01 : acc00);
#pragma unroll
            for (int qq = 0; qq < 4; ++qq) {
              int rowb = (rt2 * 2 + rsub) * 32 + qq * 8 + lkg * 4;
              *(float4*)(MsB + MS_BYTE(col, rowb)) =
                  make_float4(A[qq * 4], A[qq * 4 + 1], A[qq * 4 + 2], A[qq * 4 + 3]);
            }
          }
        }
      }
    }
    EPI_BAR();
    if (ks == 1) {
#pragma unroll
      for (int rsub = 0; rsub < 2; ++rsub) {
#pragma unroll
        for (int ct = 0; ct < 2; ++ct) {
          int col = cp * 64 + ct * 32 + lr;
          if (col < 100) {
            f32x16 A = rsub ? (ct ? acc11 : acc10) : (ct ? acc01 : acc00);
#pragma unroll
            for (int qq = 0; qq < 4; ++qq) {
              int rowb = (rt2 * 2 + rsub) * 32 + qq * 8 + lkg * 4;
              float4* mp = (float4*)(MsB + MS_BYTE(col, rowb));
              float4 old = *mp;
              *mp = make_float4(old.x + A[qq * 4], old.y + A[qq * 4 + 1],
                                old.z + A[qq * 4 + 2], old.w + A[qq * 4 + 3]);
            }
          }
        }
      }
    }
    EPI_BAR();
    // LIF over t + ballot pack -> LDS mask buffer
    const int d = lane & 31, hl = lane >> 5;
    for (int it = 0; it < 7; ++it) {
      int task = it * 16 + wid * 2 + hl;
      bool valid = task < 100;
      int hg = valid ? task / 25 : 0;
      int v = valid ? task - hg * 25 : 0;
      int row = hg * 32 + d;
      float bicv = bicL[c * 128 + row];
      float st = 0.0f;
#pragma unroll
      for (int t = 0; t < 4; ++t) {
        int colx = t * 25 + v;
        float cu = *(const float*)(MsB + MS_BYTE(colx, row)) + bicv;
        st += (cu - st) * 0.5f;
        bool sb = valid && (st >= 1.0f);
        if (st >= 1.0f) st = 0.0f;
        unsigned long long b = __ballot(sb);
        if (valid && (lane == 0 || lane == 32)) {
          uint32_t wd = (lane == 0) ? (uint32_t)b : (uint32_t)(b >> 32);
          mkL[t * 600 + br * 200 + ((c & 1) * 4 + hg) * 25 + v] = wd;
        }
      }
    }
  }

  // bulk coalesced mask store
  EPI_BAR();
  for (int i = tid; i < 2400; i += 512) {
    int t = i / 600, r = i - t * 600;
    masks[(size_t)(t * N_ + n) * 600 + r] = mkL[i];
  }
}

// ---- K2: binary attention (popcount, register-blocked) + attn_lif -> mask2 ----
__launch_bounds__(64)
__global__ void k2_attn(const uint32_t* __restrict__ masks, uint32_t* __restrict__ mask2) {
  __shared__ uint32_t qs[T_][V_], ks_[T_][V_], vs[T_][V_];
  const int n = blockIdx.x >> 3;
  const int h = blockIdx.x & 7;
  const int l = threadIdx.x;
  for (int i = l; i < T_ * 3 * V_; i += 64) {
    int t = i / (3 * V_);
    int r = i - t * (3 * V_);
    int br = r / V_;
    int v = r - br * V_;
    uint32_t w = masks[(((size_t)t * N_ + n) * 3 + br) * (H_ * V_) + h * V_ + v];
    if (br == 0) qs[t][v] = w;
    else if (br == 1) ks_[t][v] = w;
    else vs[t][v] = w;
  }
  __syncthreads();
  const int hi = l >> 5, d = l & 31;
  float st[13];
#pragma unroll
  for (int vv = 0; vv < 13; ++vv) st[vv] = 0.0f;
#pragma unroll
  for (int t = 0; t < 4; ++t) {
    uint32_t q[13];
    int y[13];
#pragma unroll
    for (int vv = 0; vv < 13; ++vv) {
      int v = vv * 2 + hi;
      q[vv] = qs[t][v < V_ ? v : 0];
      y[vv] = 0;
    }
    for (int w = 0; w < V_; ++w) {
      uint32_t kw = ks_[t][w];
      int vb = (int)((vs[t][w] >> d) & 1u);
#pragma unroll
      for (int vv = 0; vv < 13; ++vv) y[vv] += __popc(q[vv] & kw) * vb;
    }
#pragma unroll
    for (int vv = 0; vv < 13; ++vv) {
      int v = vv * 2 + hi;
      bool valid = (v < V_);
      float yf = 0.125f * (float)y[vv];
      st[vv] += (yf - st[vv]) * 0.5f;
      bool s = valid && (st[vv] >= 0.5f);
      if (st[vv] >= 0.5f) st[vv] = 0.0f;
      unsigned long long b = __ballot(s);
      if (valid && (l == 0 || l == 32)) {
        uint32_t wd = (l == 0) ? (uint32_t)b : (uint32_t)(b >> 32);
        mask2[(((size_t)t * N_ + n) * V_ + v) * H_ + h] = wd;
      }
    }
  }
}

// ---- K3: proj conv (binary B, fp16-split W) + bias/BN + LIF + residual ----
// (verbatim round-6 structure — risk contained)
__launch_bounds__(512, 2)
__global__ void k3_mfma(const float* __restrict__ x, const _Float16* __restrict__ Wstg,
                        const uint32_t* __restrict__ mask2, const float* __restrict__ bp,
                        const float* __restrict__ pg, const float* __restrict__ pb,
                        const float* __restrict__ pm, const float* __restrict__ pvar,
                        float* __restrict__ out) {
  __shared__ __align__(16) char LDSb[65536 + 32768 + 512 + 3200];
  char* Abuf = LDSb;
  char* MsB = LDSb + 65536;
  float* bic = (float*)(LDSb + 65536 + 32768);
  uint32_t* m2s = (uint32_t*)(LDSb + 65536 + 32768 + 512);

  const int n = blockIdx.x, tid = threadIdx.x;
  const int lane = tid & 63, wid = tid >> 6;
  const int rt = wid & 3, cp = wid >> 2;
  const int lr = lane & 31, lkg = lane >> 5;

  for (int i = tid; i < 800; i += 512) {
    int t = i / 200, r = i - t * 200;
    m2s[i] = mask2[(size_t)(t * N_ + n) * 200 + r];
  }
  __syncthreads();

  half8_t Bb[32];
#pragma unroll
  for (int ct = 0; ct < 2; ++ct) {
    int col = cp * 64 + ct * 32 + lr;
    bool valid = col < 100;
    int cc = valid ? col : 0;
    int t = cc / 25, v = cc - t * 25;
#pragma unroll
    for (int kt = 0; kt < 16; ++kt) {
#pragma unroll
      for (int jj = 0; jj < 8; ++jj) {
        int k = kt * 16 + lkg * 8 + jj;
        uint32_t bit = (m2s[t * 200 + v * 8 + (k >> 5)] >> (k & 31)) & 1u;
        Bb[ct * 16 + kt][jj] = (valid && bit) ? (_Float16)1.0f : (_Float16)0.0f;
      }
    }
  }
  STAGE_A(24, 0);

  for (int c = 0; c < 2; ++c) {
    f32x16 acc0 = {}, acc1 = {};
#pragma unroll
    for (int p = 0; p < 4; ++p) {
      __syncthreads();
      if (p == 0 && tid < 128) {
        int ch = c * 128 + tid;
        float sc = pg[ch] / sqrtf(pvar[ch] + 1e-5f);
        bic[tid] = fmaf(bp[ch] - pm[ch], sc, pb[ch]);
      }
      int gnext = (6 + c) * 4 + p + 1;
      if (gnext < 32) STAGE_A(gnext, (p + 1) & 1);
#pragma unroll
      for (int s = 0; s < 4; ++s) {
        const char* kb = Abuf + (p & 1) * 32768 + s * 8192 + rt * 1024 + lane * 16;
        half8_t Ahi = *(const half8_t*)(kb);
        half8_t Alo = *(const half8_t*)(kb + 4096);
        const int kt = p * 4 + s;
        __builtin_amdgcn_s_setprio(1);
        acc0 = mfma16(Ahi, Bb[kt], acc0);
        acc1 = mfma16(Ahi, Bb[16 + kt], acc1);
        acc0 = mfma16(Alo, Bb[kt], acc0);
        acc1 = mfma16(Alo, Bb[16 + kt], acc1);
        __builtin_amdgcn_s_setprio(0);
      }
    }

    __syncthreads();
#pragma unroll
    for (int ct = 0; ct < 2; ++ct) {
      int col = cp * 64 + ct * 32 + lr;
      if (col < 100) {
        f32x16 A = ct ? acc1 : acc0;
#pragma unroll
        for (int qq = 0; qq < 4; ++qq) {
          int rowb = rt * 32 + qq * 8 + lkg * 4;
          *(float4*)(MsB + MS_BYTE(col, rowb)) =
              make_float4(A[qq * 4], A[qq * 4 + 1], A[qq * 4 + 2], A[qq * 4 + 3]);
        }
      }
    }
    __syncthreads();
    const int d = lane & 31, hl = lane >> 5;
    for (int it = 0; it < 7; ++it) {
      int task = it * 16 + wid * 2 + hl;
      bool valid = task < 100;
      int hg = valid ? task / 25 : 0;
      int v = valid ? task - hg * 25 : 0;
      int row = hg * 32 + d;
      float bicv = bic[row];
      float st = 0.0f;
#pragma unroll
      for (int t = 0; t < 4; ++t) {
        int colx = t * 25 + v;
        char* mp = MsB + MS_BYTE(colx, row);
        if (valid) {
          float cu = *(const float*)(mp) + bicv;
          st += (cu - st) * 0.5f;
          float sv = (st >= 1.0f) ? 1.0f : 0.0f;
          if (st >= 1.0f) st = 0.0f;
          *(float*)(mp) = sv;
        }
      }
    }
    __syncthreads();
    for (int ii = tid; ii < 12800; ii += 512) {
      int t = ii / 3200, r2 = ii - t * 3200;
      int cl = r2 / 25, v = r2 - cl * 25;
      int colx = t * 25 + v;
      float sv = *(const float*)(MsB + MS_BYTE(colx, cl));
      size_t go = (size_t)(t * N_ + n) * 6400 + (size_t)(c * 128 + cl) * 25 + v;
      out[go] = sv + x[go];
    }
  }
}

extern "C" void kernel_launch(void* const* d_in, const int* in_sizes, int n_in,
                              void* d_out, int out_size, void* d_ws, size_t ws_size,
                              hipStream_t stream) {
  const float* x    = (const float*)d_in[0];
  const float* wq   = (const float*)d_in[1];
  const float* wk   = (const float*)d_in[2];
  const float* wv   = (const float*)d_in[3];
  const float* wp   = (const float*)d_in[4];
  const float* bp   = (const float*)d_in[5];
  const float* qg   = (const float*)d_in[6];
  const float* qb   = (const float*)d_in[7];
  const float* qm   = (const float*)d_in[8];
  const float* qvar = (const float*)d_in[9];
  const float* kg   = (const float*)d_in[10];
  const float* kb   = (const float*)d_in[11];
  const float* km   = (const float*)d_in[12];
  const float* kvar = (const float*)d_in[13];
  const float* vg   = (const float*)d_in[14];
  const float* vb   = (const float*)d_in[15];
  const float* vm   = (const float*)d_in[16];
  const float* vvar = (const float*)d_in[17];
  const float* pg   = (const float*)d_in[18];
  const float* pb   = (const float*)d_in[19];
  const float* pm   = (const float*)d_in[20];
  const float* pvar = (const float*)d_in[21];

  _Float16* Wstg = (_Float16*)d_ws;                      // 1 MB
  _Float16* X16  = (_Float16*)d_ws + 524288;             // 52.4 MB panels
  uint32_t* masks = (uint32_t*)((char*)d_ws + 1048576 + 52428800);
  uint32_t* mask2 = masks + 1228800;

  kw_stage<<<1024, 512, 0, stream>>>(wq, wk, wv, wp, qg, qvar, kg, kvar,
                                     vg, vvar, pg, pvar, Wstg);
  kx_stage<<<512, 256, 0, stream>>>(x, X16);
  k1_mfma<<<512, 512, 0, stream>>>(X16, Wstg, qg, qb, qm, qvar, kg, kb, km, kvar,
                                   vg, vb, vm, vvar, masks);
  k2_attn<<<4096, 64, 0, stream>>>(masks, mask2);
  k3_mfma<<<512, 512, 0, stream>>>(x, Wstg, mask2, bp, pg, pb, pm, pvar, (float*)d_out);
}

// Round 8
// 282.486 us; speedup vs baseline: 1.6243x; 1.0264x over previous
//
#include <hip/hip_runtime.h>
#include <cstdint>
#include <cstddef>

#define T_ 4
#define N_ 512
#define C_ 256
#define V_ 25
#define H_ 8

typedef _Float16 half8_t __attribute__((ext_vector_type(8)));
typedef float f32x16 __attribute__((ext_vector_type(16)));

__device__ __forceinline__ f32x16 mfma16(half8_t a, half8_t b, f32x16 c) {
  return __builtin_amdgcn_mfma_f32_32x32x16_f16(a, b, c, 0, 0, 0);
}

// ---- KW: pre-swizzled, BN-scaled, fp16-split weights (verbatim r7) ----
// Wstg: i = ((((c*4+p)*4+s)*2+m)*4+rt)*512 + lane*8 + j
//   chunks 0..5 = qkv (br=c>>1, rows (c&1)*128+..), 6..7 = proj
__global__ void kw_stage(const float* __restrict__ wq, const float* __restrict__ wk,
                         const float* __restrict__ wv, const float* __restrict__ wp,
                         const float* __restrict__ qg, const float* __restrict__ qvar,
                         const float* __restrict__ kg, const float* __restrict__ kvar,
                         const float* __restrict__ vg, const float* __restrict__ vvar,
                         const float* __restrict__ pg, const float* __restrict__ pvar,
                         _Float16* __restrict__ Wstg) {
  int i = blockIdx.x * 512 + threadIdx.x;          // < 524288
  int j = i & 7, lane = (i >> 3) & 63, rt = (i >> 9) & 3, m = (i >> 11) & 1;
  int s = (i >> 12) & 3, p = (i >> 14) & 3, c = i >> 16;
  int kt = p * 4 + s;
  int row = rt * 32 + (lane & 31);
  int k = kt * 16 + (lane >> 5) * 8 + j;
  const float *w, *g, *va;
  int grow;
  if (c < 6) {
    int br = c >> 1;
    w = br == 0 ? wq : br == 1 ? wk : wv;
    g = br == 0 ? qg : br == 1 ? kg : vg;
    va = br == 0 ? qvar : br == 1 ? kvar : vvar;
    grow = (c & 1) * 128 + row;
  } else {
    w = wp; g = pg; va = pvar;
    grow = (c - 6) * 128 + row;
  }
  float sc = g[grow] / sqrtf(va[grow] + 1e-5f);
  float wv_ = w[grow * 256 + k] * sc;
  _Float16 hi = (_Float16)wv_;
  Wstg[i] = (m == 0) ? hi : (_Float16)(wv_ - (float)hi);
}

// Ms swizzled byte offset (verbatim — bit-exact r4-r7)
#define MS_BYTE(colx, rowx) ((colx) * 256 + (((rowx) * 4) ^ (((colx) & 7) << 4)))

// A-fragment loads, straight from global (L2-resident Wstg), offsets in halves
#define QKV_LD(AH0, AH1, AL0, AL1, cc, gg)                                            \
  do {                                                                                \
    const _Float16* bp_ = Wstg + ((size_t)((cc) * 4 + ((gg) >> 1)) << 14) +           \
                          ((size_t)((((gg) & 1) * 2 + ks)) << 12) +                   \
                          ((rt2 * 2) << 9) + (lane << 3);                             \
    AH0 = *(const half8_t*)(bp_);                                                     \
    AH1 = *(const half8_t*)(bp_ + 512);                                               \
    AL0 = *(const half8_t*)(bp_ + 2048);                                              \
    AL1 = *(const half8_t*)(bp_ + 2048 + 512);                                        \
  } while (0)

#define QKV_MMA(AH0, AH1, AL0, AL1, BI)                                               \
  do {                                                                                \
    __builtin_amdgcn_s_setprio(1);                                                    \
    acc00 = mfma16(AH0, Bh[BI], acc00);                                               \
    acc01 = mfma16(AH0, Bh[8 + BI], acc01);                                           \
    acc10 = mfma16(AH1, Bh[BI], acc10);                                               \
    acc11 = mfma16(AH1, Bh[8 + BI], acc11);                                           \
    acc00 = mfma16(AH0, Bl[BI], acc00);                                               \
    acc01 = mfma16(AH0, Bl[8 + BI], acc01);                                           \
    acc10 = mfma16(AH1, Bl[BI], acc10);                                               \
    acc11 = mfma16(AH1, Bl[8 + BI], acc11);                                           \
    acc00 = mfma16(AL0, Bh[BI], acc00);                                               \
    acc01 = mfma16(AL0, Bh[8 + BI], acc01);                                           \
    acc10 = mfma16(AL1, Bh[BI], acc10);                                               \
    acc11 = mfma16(AL1, Bh[8 + BI], acc11);                                           \
    __builtin_amdgcn_s_setprio(0);                                                    \
  } while (0)

#define PRJ_LD(AHI, ALO, cc, kk)                                                      \
  do {                                                                                \
    const _Float16* bp_ = Wstg + ((size_t)(24 + (cc) * 4 + ((kk) >> 2)) << 14) +      \
                          ((size_t)((kk) & 3) << 12) + (rt3 << 9) + (lane << 3);      \
    AHI = *(const half8_t*)(bp_);                                                     \
    ALO = *(const half8_t*)(bp_ + 2048);                                              \
  } while (0)

// ---- K1 fused: qkv conv + BN + LIF + binary attention + attn_lif + proj conv
//      + bias/BN + LIF + residual.  block = one n, 8 waves.
__launch_bounds__(512, 2)
__global__ void k1_fused(const float* __restrict__ x, const _Float16* __restrict__ Wstg,
                         const float* __restrict__ qg, const float* __restrict__ qb,
                         const float* __restrict__ qm, const float* __restrict__ qvar,
                         const float* __restrict__ kg, const float* __restrict__ kb,
                         const float* __restrict__ km, const float* __restrict__ kvar,
                         const float* __restrict__ vg, const float* __restrict__ vb,
                         const float* __restrict__ vm, const float* __restrict__ vvar,
                         const float* __restrict__ bp, const float* __restrict__ pg,
                         const float* __restrict__ pb, const float* __restrict__ pm,
                         const float* __restrict__ pvar, float* __restrict__ out) {
  __shared__ __align__(16) char LDSb[48640];
  char* MsB = LDSb;                            // 32768
  float* bicL = (float*)(LDSb + 32768);        // 768 f32
  uint32_t* mkL = (uint32_t*)(LDSb + 35840);   // 2400 u32 (q/k/v spike masks)
  uint32_t* m2L = (uint32_t*)(LDSb + 45440);   // 800 u32 (attn spike masks)

  const int n = blockIdx.x, tid = threadIdx.x;
  const int lane = tid & 63, wid = tid >> 6;
  const int ks = wid & 1, cp = (wid >> 1) & 1, rt2 = wid >> 2;
  const int lr = lane & 31, lkg = lane >> 5;

  // hoisted BN-bias table for the 6 qkv chunks
  for (int i = tid; i < 768; i += 512) {
    int cc = i >> 7, row = i & 127;
    int br = cc >> 1, ch = (cc & 1) * 128 + row;
    const float* g  = br == 0 ? qg : br == 1 ? kg : vg;
    const float* be = br == 0 ? qb : br == 1 ? kb : vb;
    const float* mu = br == 0 ? qm : br == 1 ? km : vm;
    const float* va = br == 0 ? qvar : br == 1 ? kvar : vvar;
    float sc = g[ch] / sqrtf(va[ch] + 1e-5f);
    bicL[i] = be[ch] - mu[ch] * sc;
  }

  // B-bank straight from x: fp16 hi/lo split, this wave's K-parity half, 2 col-tiles
  half8_t Bh[16], Bl[16];
#pragma unroll
  for (int ct = 0; ct < 2; ++ct) {
    int col = cp * 64 + ct * 32 + lr;
    bool valid = col < 100;
    int cc = valid ? col : 0;
    int t = cc / 25, v = cc - t * 25;
    const float* xb = x + (size_t)(t * N_ + n) * 6400 + v;
#pragma unroll
    for (int ktl = 0; ktl < 8; ++ktl) {
      int k0 = (ktl * 2 + ks) * 16 + lkg * 8;
#pragma unroll
      for (int e = 0; e < 8; ++e) {
        float f = valid ? xb[(k0 + e) * 25] : 0.0f;
        _Float16 h = (_Float16)f;
        Bh[ct * 8 + ktl][e] = h;
        Bl[ct * 8 + ktl][e] = (_Float16)(f - (float)h);
      }
    }
  }
  __syncthreads();     // bicL visible

  // ---------- qkv phase: 6 chunks, A from L2, 1-group register prefetch ----------
  half8_t a0h0, a0h1, a0l0, a0l1, a1h0, a1h1, a1l0, a1l1;
  QKV_LD(a0h0, a0h1, a0l0, a0l1, 0, 0);
  for (int c = 0; c < 6; ++c) {
    const int br = c >> 1;
    f32x16 acc00 = {}, acc01 = {}, acc10 = {}, acc11 = {};
#pragma unroll
    for (int g = 0; g < 8; ++g) {
      if ((g & 1) == 0) {
        if (g < 7) QKV_LD(a1h0, a1h1, a1l0, a1l1, c, g + 1);
        QKV_MMA(a0h0, a0h1, a0l0, a0l1, g);
      } else {
        if (g < 7) QKV_LD(a0h0, a0h1, a0l0, a0l1, c, g + 1);
        else if (c < 5) QKV_LD(a0h0, a0h1, a0l0, a0l1, c + 1, 0);
        QKV_MMA(a1h0, a1h1, a1l0, a1l1, g);
      }
    }

    // epilogue (verbatim r7): ks0 writes partials, ks1 adds, LIF + ballot -> mkL
    __syncthreads();
    if (ks == 0) {
#pragma unroll
      for (int rsub = 0; rsub < 2; ++rsub) {
#pragma unroll
        for (int ct = 0; ct < 2; ++ct) {
          int col = cp * 64 + ct * 32 + lr;
          if (col < 100) {
            f32x16 A = rsub ? (ct ? acc11 : acc10) : (ct ? acc01 : acc00);
#pragma unroll
            for (int qq = 0; qq < 4; ++qq) {
              int rowb = (rt2 * 2 + rsub) * 32 + qq * 8 + lkg * 4;
              *(float4*)(MsB + MS_BYTE(col, rowb)) =
                  make_float4(A[qq * 4], A[qq * 4 + 1], A[qq * 4 + 2], A[qq * 4 + 3]);
            }
          }
        }
      }
    }
    __syncthreads();
    if (ks == 1) {
#pragma unroll
      for (int rsub = 0; rsub < 2; ++rsub) {
#pragma unroll
        for (int ct = 0; ct < 2; ++ct) {
          int col = cp * 64 + ct * 32 + lr;
          if (col < 100) {
            f32x16 A = rsub ? (ct ? acc11 : acc10) : (ct ? acc01 : acc00);
#pragma unroll
            for (int qq = 0; qq < 4; ++qq) {
              int rowb = (rt2 * 2 + rsub) * 32 + qq * 8 + lkg * 4;
              float4* mp = (float4*)(MsB + MS_BYTE(col, rowb));
              float4 old = *mp;
              *mp = make_float4(old.x + A[qq * 4], old.y + A[qq * 4 + 1],
                                old.z + A[qq * 4 + 2], old.w + A[qq * 4 + 3]);
            }
          }
        }
      }
    }
    __syncthreads();
    const int d = lane & 31, hl = lane >> 5;
    for (int it = 0; it < 7; ++it) {
      int task = it * 16 + wid * 2 + hl;
      bool valid = task < 100;
      int hg = valid ? task / 25 : 0;
      int v = valid ? task - hg * 25 : 0;
      int row = hg * 32 + d;
      float bicv = bicL[c * 128 + row];
      float st = 0.0f;
#pragma unroll
      for (int t = 0; t < 4; ++t) {
        int colx = t * 25 + v;
        float cu = *(const float*)(MsB + MS_BYTE(colx, row)) + bicv;
        st += (cu - st) * 0.5f;
        bool sb = valid && (st >= 1.0f);
        if (st >= 1.0f) st = 0.0f;
        unsigned long long b = __ballot(sb);
        if (valid && (lane == 0 || lane == 32)) {
          uint32_t wd = (lane == 0) ? (uint32_t)b : (uint32_t)(b >> 32);
          mkL[t * 600 + br * 200 + ((c & 1) * 4 + hg) * 25 + v] = wd;
        }
      }
    }
  }
  __syncthreads();     // mkL complete

  // ---------- attention phase: wave = head h, exact popcount + attn_lif ----------
  {
    const int h = wid, hi2 = lane >> 5, d = lane & 31;
    float st2[13];
#pragma unroll
    for (int vv = 0; vv < 13; ++vv) st2[vv] = 0.0f;
#pragma unroll
    for (int t = 0; t < 4; ++t) {
      uint32_t q[13];
      int y[13];
#pragma unroll
      for (int vv = 0; vv < 13; ++vv) {
        int v = vv * 2 + hi2;
        q[vv] = mkL[t * 600 + h * 25 + (v < V_ ? v : 0)];
        y[vv] = 0;
      }
      for (int w = 0; w < V_; ++w) {
        uint32_t kw2 = mkL[t * 600 + 200 + h * 25 + w];
        int vb = (int)((mkL[t * 600 + 400 + h * 25 + w] >> d) & 1u);
#pragma unroll
        for (int vv = 0; vv < 13; ++vv) y[vv] += __popc(q[vv] & kw2) * vb;
      }
#pragma unroll
      for (int vv = 0; vv < 13; ++vv) {
        int v = vv * 2 + hi2;
        bool valid = (v < V_);
        float yf = 0.125f * (float)y[vv];
        st2[vv] += (yf - st2[vv]) * 0.5f;
        bool s = valid && (st2[vv] >= 0.5f);
        if (st2[vv] >= 0.5f) st2[vv] = 0.0f;
        unsigned long long b = __ballot(s);
        if (valid && (lane == 0 || lane == 32)) {
          uint32_t wd = (lane == 0) ? (uint32_t)b : (uint32_t)(b >> 32);
          m2L[t * 200 + v * 8 + h] = wd;
        }
      }
    }
  }
  __syncthreads();     // m2L complete

  // ---------- proj phase: binary B from m2L, A from L2 chunks 6-7 ----------
  const int rt3 = wid & 3, cp3 = wid >> 2;
  half8_t Bb[32];
#pragma unroll
  for (int ct = 0; ct < 2; ++ct) {
    int col = cp3 * 64 + ct * 32 + lr;
    bool valid = col < 100;
    int cc = valid ? col : 0;
    int t = cc / 25, v = cc - t * 25;
#pragma unroll
    for (int kt = 0; kt < 16; ++kt) {
#pragma unroll
      for (int jj = 0; jj < 8; ++jj) {
        int k = kt * 16 + lkg * 8 + jj;
        uint32_t bit = (m2L[t * 200 + v * 8 + (k >> 5)] >> (k & 31)) & 1u;
        Bb[ct * 16 + kt][jj] = (valid && bit) ? (_Float16)1.0f : (_Float16)0.0f;
      }
    }
  }
  if (tid < 256) {
    float sc = pg[tid] / sqrtf(pvar[tid] + 1e-5f);
    bicL[tid] = fmaf(bp[tid] - pm[tid], sc, pb[tid]);
  }

  half8_t p0h, p0l, p1h, p1l;
  PRJ_LD(p0h, p0l, 0, 0);
  for (int c = 0; c < 2; ++c) {
    f32x16 acc0 = {}, acc1 = {};
#pragma unroll
    for (int kt = 0; kt < 16; ++kt) {
      if ((kt & 1) == 0) {
        if (kt < 15) PRJ_LD(p1h, p1l, c, kt + 1);
        __builtin_amdgcn_s_setprio(1);
        acc0 = mfma16(p0h, Bb[kt], acc0);
        acc1 = mfma16(p0h, Bb[16 + kt], acc1);
        acc0 = mfma16(p0l, Bb[kt], acc0);
        acc1 = mfma16(p0l, Bb[16 + kt], acc1);
        __builtin_amdgcn_s_setprio(0);
      } else {
        if (kt < 15) PRJ_LD(p0h, p0l, c, kt + 1);
        else if (c < 1) PRJ_LD(p0h, p0l, 1, 0);
        __builtin_amdgcn_s_setprio(1);
        acc0 = mfma16(p1h, Bb[kt], acc0);
        acc1 = mfma16(p1h, Bb[16 + kt], acc1);
        acc0 = mfma16(p1l, Bb[kt], acc0);
        acc1 = mfma16(p1l, Bb[16 + kt], acc1);
        __builtin_amdgcn_s_setprio(0);
      }
    }

    __syncthreads();   // Ms free (prev reads done) + bicL visible
#pragma unroll
    for (int ct = 0; ct < 2; ++ct) {
      int col = cp3 * 64 + ct * 32 + lr;
      if (col < 100) {
        f32x16 A = ct ? acc1 : acc0;
#pragma unroll
        for (int qq = 0; qq < 4; ++qq) {
          int rowb = rt3 * 32 + qq * 8 + lkg * 4;
          *(float4*)(MsB + MS_BYTE(col, rowb)) =
              make_float4(A[qq * 4], A[qq * 4 + 1], A[qq * 4 + 2], A[qq * 4 + 3]);
        }
      }
    }
    __syncthreads();
    // LIF (v_th=1.0): write spike back into Ms
    const int d = lane & 31, hl = lane >> 5;
    for (int it = 0; it < 7; ++it) {
      int task = it * 16 + wid * 2 + hl;
      bool valid = task < 100;
      int hg = valid ? task / 25 : 0;
      int v = valid ? task - hg * 25 : 0;
      int row = hg * 32 + d;
      float bicv = bicL[c * 128 + row];
      float st = 0.0f;
#pragma unroll
      for (int t = 0; t < 4; ++t) {
        int colx = t * 25 + v;
        char* mp = MsB + MS_BYTE(colx, row);
        if (valid) {
          float cu = *(const float*)(mp) + bicv;
          st += (cu - st) * 0.5f;
          float sv = (st >= 1.0f) ? 1.0f : 0.0f;
          if (st >= 1.0f) st = 0.0f;
          *(float*)(mp) = sv;
        }
      }
    }
    __syncthreads();
    // residual + coalesced store
    for (int ii = tid; ii < 12800; ii += 512) {
      int t = ii / 3200, r2 = ii - t * 3200;
      int cl = r2 / 25, v = r2 - cl * 25;
      int colx = t * 25 + v;
      float sv = *(const float*)(MsB + MS_BYTE(colx, cl));
      size_t go = (size_t)(t * N_ + n) * 6400 + (size_t)(c * 128 + cl) * 25 + v;
      out[go] = sv + x[go];
    }
  }
}

extern "C" void kernel_launch(void* const* d_in, const int* in_sizes, int n_in,
                              void* d_out, int out_size, void* d_ws, size_t ws_size,
                              hipStream_t stream) {
  const float* x    = (const float*)d_in[0];
  const float* wq   = (const float*)d_in[1];
  const float* wk   = (const float*)d_in[2];
  const float* wv   = (const float*)d_in[3];
  const float* wp   = (const float*)d_in[4];
  const float* bp   = (const float*)d_in[5];
  const float* qg   = (const float*)d_in[6];
  const float* qb   = (const float*)d_in[7];
  const float* qm   = (const float*)d_in[8];
  const float* qvar = (const float*)d_in[9];
  const float* kg   = (const float*)d_in[10];
  const float* kb   = (const float*)d_in[11];
  const float* km   = (const float*)d_in[12];
  const float* kvar = (const float*)d_in[13];
  const float* vg   = (const float*)d_in[14];
  const float* vb   = (const float*)d_in[15];
  const float* vm   = (const float*)d_in[16];
  const float* vvar = (const float*)d_in[17];
  const float* pg   = (const float*)d_in[18];
  const float* pb   = (const float*)d_in[19];
  const float* pm   = (const float*)d_in[20];
  const float* pvar = (const float*)d_in[21];

  _Float16* Wstg = (_Float16*)d_ws;   // 1 MB pre-swizzled weights

  kw_stage<<<1024, 512, 0, stream>>>(wq, wk, wv, wp, qg, qvar, kg, kvar,
                                     vg, vvar, pg, pvar, Wstg);
  k1_fused<<<512, 512, 0, stream>>>(x, Wstg, qg, qb, qm, qvar, kg, kb, km, kvar,
                                    vg, vb, vm, vvar, bp, pg, pb, pm, pvar,
                                    (float*)d_out);
}